// Round 2
// baseline (280.556 us; speedup 1.0000x reference)
//
#include <hip/hip_runtime.h>

using bf16x8 = __attribute__((ext_vector_type(8))) short;
using f32x4  = __attribute__((ext_vector_type(4))) float;
using u32x4  = __attribute__((ext_vector_type(4))) unsigned int;

__device__ __forceinline__ unsigned short f2bf(float f) {
  unsigned int u = __builtin_bit_cast(unsigned int, f);
  u += 0x7FFF + ((u >> 16) & 1);               // RNE
  return (unsigned short)(u >> 16);
}
__device__ __forceinline__ bf16x8 lds_frag(const unsigned short* p) {
  return __builtin_bit_cast(bf16x8, *(const u32x4*)p);
}
// async global->LDS, 16B per lane; LDS dest = wave-uniform base + lane*16
__device__ __forceinline__ void async_copy16(const unsigned short* g, unsigned short* l) {
  __builtin_amdgcn_global_load_lds(
      (const __attribute__((address_space(1))) unsigned int*)g,
      (__attribute__((address_space(3))) unsigned int*)l, 16, 0, 0);
}

// fp32 -> bf16 elementwise, 8 elems/thread
__global__ void cast_bf16_k(const float* __restrict__ in,
                            unsigned short* __restrict__ out, int n) {
  int i = (blockIdx.x * 256 + threadIdx.x) * 8;
  if (i < n) {
    unsigned short r[8];
    #pragma unroll
    for (int j = 0; j < 8; ++j) r[j] = f2bf(in[i + j]);
    *(u32x4*)&out[i] = *(u32x4*)r;
  }
}

// LDS-tiled transpose+cast: out[c*R+r] = bf16(in[r*C+c]). R,C multiples of 32.
__global__ void transpose_cast_k(const float* __restrict__ in,
                                 unsigned short* __restrict__ out, int R, int C) {
  __shared__ float tile[32][33];
  const int tx = threadIdx.x & 31, ty = threadIdx.x >> 5;   // 32 x 8
  const int c0 = blockIdx.x * 32, r0 = blockIdx.y * 32;
  #pragma unroll
  for (int i = 0; i < 4; ++i)
    tile[ty + i * 8][tx] = in[(size_t)(r0 + ty + i * 8) * C + c0 + tx];
  __syncthreads();
  #pragma unroll
  for (int i = 0; i < 4; ++i)
    out[(size_t)(c0 + ty + i * 8) * R + r0 + tx] = f2bf(tile[tx][ty + i * 8]);
}

// C[M,N] = A[M,K] @ Bt[N,K]^T (+bias for fp32 out), bf16 in, fp32 accum.
// 256x256 tile, BK=64, 512 threads (8 waves, 2M x 4N), double-buffered LDS.
// LDS layout: per buffer, per matrix, TWO k-half planes [256 rows][32 k],
// XOR-4 swizzle within a plane: 16B-group slot s holds global group s^(row&3)
// -> ds_read_b128 frag reads are bank-conflict-free, and each plane is a
// linear global_load_lds destination (swizzle applied on the global source).
// Schedule per K-tile T (2 barriers, 2 counted waits — no vmcnt(0) in loop):
//   lgkm0; vmcnt(4); barrier          // publishes T.ks0 (issued 1 tile ago)
//   issue 8 loads of tile T+1 -> buf^1 (ks0 group, fence, ks1 group)
//   compute KS0 (B-frags x4 + A-frags x8, 32 MFMA, setprio)
//   lgkm0; vmcnt(8); barrier          // publishes T.ks1
//   compute KS1
// Race-freedom: each LDS region has exactly one barrier between its last read
// (lgkm-drained before that barrier) and the staging that overwrites it.
// Issue-order fences make the counted vmcnt subsets well-defined.
template <typename OutT>
__global__ __launch_bounds__(512, 2)
void gemm_bt256(const unsigned short* __restrict__ A,
                const unsigned short* __restrict__ Bt,
                OutT* __restrict__ C,
                const float* __restrict__ bias,
                int M, int N, int K, int n_tiles, int mt_per_xcd) {
  __shared__ unsigned short Ash[2][2][256 * 32];   // [buf][ks][row*32+k] 64 KB
  __shared__ unsigned short Bsh[2][2][256 * 32];   // 64 KB
  const int tid  = threadIdx.x;                 // 0..511
  const int wv   = tid >> 6, lane = tid & 63;
  const int quad = lane >> 4, l15 = lane & 15;
  const int wr   = wv >> 2, wc = wv & 3;        // 2M x 4N wave grid

  const int b = blockIdx.x;
  const int xcd = b & 7, local = b >> 3;        // grid % 8 == 0 -> bijective
  const int mt = xcd * mt_per_xcd + local / n_tiles;
  const int nt = local % n_tiles;
  const int m0 = mt * 256, n0 = nt * 256;

  // staging addresses: per plane, lin = i*512+tid (i in 0..1) covers 1024 16B
  // groups; LDS slot lin -> (row = lin>>2, s = lin&3), global group g = s^(row&3)
  const unsigned short* gA[2];
  const unsigned short* gB[2];
  int loff[2];
  #pragma unroll
  for (int i = 0; i < 2; ++i) {
    int lin = i * 512 + tid;
    int row = lin >> 2, g = (lin & 3) ^ (row & 3);
    gA[i] = &A[(size_t)(m0 + row) * K + g * 8];
    gB[i] = &Bt[(size_t)(n0 + row) * K + g * 8];
    loff[i] = lin * 8;                          // shorts (lin*16 bytes)
  }

  f32x4 acc[8][4];
  #pragma unroll
  for (int i = 0; i < 8; ++i)
    #pragma unroll
    for (int j = 0; j < 4; ++j)
      acc[i][j] = (f32x4){0.f, 0.f, 0.f, 0.f};

  const int arow = wr * 128 + l15;
  const int brow = wc * 64 + l15;
  const int sw   = (quad ^ (l15 & 3)) * 8;      // per-thread swizzled k-group

  // issue all 8 loads of one K-tile into buffer dst; ks0 group strictly older
  // than ks1 group (fence) so vmcnt(4)/vmcnt(8) select well-defined subsets
  auto stage = [&](int dst, int koff) {
    #pragma unroll
    for (int i = 0; i < 2; ++i) async_copy16(gA[i] + koff,      &Ash[dst][0][loff[i]]);
    #pragma unroll
    for (int i = 0; i < 2; ++i) async_copy16(gB[i] + koff,      &Bsh[dst][0][loff[i]]);
    asm volatile("" ::: "memory");              // order ks0 group before ks1 group
    #pragma unroll
    for (int i = 0; i < 2; ++i) async_copy16(gA[i] + koff + 32, &Ash[dst][1][loff[i]]);
    #pragma unroll
    for (int i = 0; i < 2; ++i) async_copy16(gB[i] + koff + 32, &Bsh[dst][1][loff[i]]);
  };

  auto compute_half = [&](int buf, int ks) {
    const unsigned short* As = &Ash[buf][ks][0];
    const unsigned short* Bs = &Bsh[buf][ks][0];
    bf16x8 bfr[4];
    #pragma unroll
    for (int n = 0; n < 4; ++n)
      bfr[n] = lds_frag(&Bs[(brow + n * 16) * 32 + sw]);
    #pragma unroll
    for (int mh = 0; mh < 2; ++mh) {
      bf16x8 af[4];
      #pragma unroll
      for (int m = 0; m < 4; ++m)
        af[m] = lds_frag(&As[(arow + mh * 64 + m * 16) * 32 + sw]);
      __builtin_amdgcn_s_setprio(1);
      #pragma unroll
      for (int m = 0; m < 4; ++m)
        #pragma unroll
        for (int n = 0; n < 4; ++n)
          acc[mh * 4 + m][n] = __builtin_amdgcn_mfma_f32_16x16x32_bf16(
              af[m], bfr[n], acc[mh * 4 + m][n], 0, 0, 0);
      __builtin_amdgcn_s_setprio(0);
    }
  };

  const int NT = K >> 6;                        // K-tiles (even: 16 or 8 here)
  stage(0, 0);                                  // prologue: tile 0 -> buf0

  for (int T = 0; T < NT; ++T) {
    const int buf = T & 1;
    // ---- half-phase 1 entry: publish T.ks0 ----
    asm volatile("s_waitcnt lgkmcnt(0)" ::: "memory");
    asm volatile("s_waitcnt vmcnt(4)" ::: "memory");
    __builtin_amdgcn_s_barrier();
    asm volatile("" ::: "memory");
    if (T + 1 < NT) stage(buf ^ 1, (T + 1) * 64);
    compute_half(buf, 0);
    // ---- half-phase 2 entry: publish T.ks1 ----
    asm volatile("s_waitcnt lgkmcnt(0)" ::: "memory");
    if (T + 1 < NT) asm volatile("s_waitcnt vmcnt(8)" ::: "memory");
    else            asm volatile("s_waitcnt vmcnt(0)" ::: "memory");
    __builtin_amdgcn_s_barrier();
    asm volatile("" ::: "memory");
    compute_half(buf, 1);
  }

  #pragma unroll
  for (int mf = 0; mf < 8; ++mf) {
    #pragma unroll
    for (int n = 0; n < 4; ++n) {
      int col = n0 + wc * 64 + n * 16 + l15;
      float badd = (bias != nullptr) ? bias[col] : 0.f;
      #pragma unroll
      for (int r = 0; r < 4; ++r) {
        int row = m0 + wr * 128 + mf * 16 + quad * 4 + r;
        if constexpr (sizeof(OutT) == 2)
          C[(size_t)row * N + col] = f2bf(acc[mf][n][r] + badd);
        else
          C[(size_t)row * N + col] = acc[mf][n][r] + badd;
      }
    }
  }
}

// Local attention: one block per (head, window). qkv: 16384 x 1536 bf16,
// out: 16384 x 512 bf16. WSZ=128, lookback window of 128 (zeros for w==0).
// mask: col <= row + 128. scale = 1/8.
__global__ __launch_bounds__(256, 2)
void attn_local(const unsigned short* __restrict__ qkv,
                unsigned short* __restrict__ out) {
  // Ksh: [ks(2)][j(256)][32] (64B rows -> b128 frags). Psh overlays Ksh.
  // VshT: V^T col-major [n(64)][k(256)], XOR swizzle: 16B-group g of row n at
  // slot g^(n&7) -> both staging stores and PV frag reads are conflict-optimal.
  __shared__ unsigned short Ksh[2 * 256 * 32];   // 32 KB
  __shared__ unsigned short VshT[64 * 256];      // 32 KB
  unsigned short* Psh = Ksh;

  const int tid  = threadIdx.x;
  const int wv   = tid >> 6, lane = tid & 63;
  const int quad = lane >> 4, l15 = lane & 15;
  const int h = blockIdx.x & 7, w = blockIdx.x >> 3;

  // stage K (k-tiled); rows j<128 of window 0 are zeros
  #pragma unroll
  for (int p = 0; p < 8; ++p) {
    int c = p * 256 + tid;                 // 2048 = 256 rows x 8 vec8-groups
    int j = c >> 3, sub = c & 7;
    u32x4 kvv = (u32x4){0, 0, 0, 0};
    if (!(w == 0 && j < 128)) {
      size_t base = (size_t)((w - 1) * 128 + j) * 1536 + h * 64 + sub * 8;
      kvv = *(const u32x4*)&qkv[base + 512];
    }
    *(u32x4*)&Ksh[(sub >> 2) * 8192 + j * 32 + (sub & 3) * 8] = kvv;
  }
  // stage V^T: thread (n = tid&63, kb4 = tid>>6) loads column n, 8 k's per iter
  {
    const int n = tid & 63, kb4 = tid >> 6;
    #pragma unroll
    for (int kk = 0; kk < 8; ++kk) {
      int kb = kk * 4 + kb4;               // group 0..31, k0 = kb*8
      unsigned short tmp[8];
      if (w == 0 && kb < 16) {
        #pragma unroll
        for (int j = 0; j < 8; ++j) tmp[j] = 0;
      } else {
        #pragma unroll
        for (int j = 0; j < 8; ++j)
          tmp[j] = qkv[(size_t)((w - 1) * 128 + kb * 8 + j) * 1536 + 1024 + h * 64 + n];
      }
      *(u32x4*)&VshT[n * 256 + ((kb ^ (n & 7)) * 8)] = *(u32x4*)tmp;
    }
  }
  __syncthreads();

  // Q fragments straight from global (A-operand: row l15, k = ks*32+quad*8..+7)
  bf16x8 qf[2][2];
  #pragma unroll
  for (int mt = 0; mt < 2; ++mt) {
    int tok = w * 128 + (wv * 2 + mt) * 16 + l15;
    #pragma unroll
    for (int ks = 0; ks < 2; ++ks)
      qf[mt][ks] = __builtin_bit_cast(
          bf16x8, *(const u32x4*)&qkv[(size_t)tok * 1536 + h * 64 + ks * 32 + quad * 8]);
  }

  // scores: wave wv owns rows [wv*32, wv*32+32) => m-tiles {2wv, 2wv+1}
  float s[2][16][4];
  #pragma unroll
  for (int nt = 0; nt < 16; ++nt) {
    bf16x8 kf0 = lds_frag(&Ksh[0    + (nt * 16 + l15) * 32 + quad * 8]);
    bf16x8 kf1 = lds_frag(&Ksh[8192 + (nt * 16 + l15) * 32 + quad * 8]);
    #pragma unroll
    for (int mt = 0; mt < 2; ++mt) {
      f32x4 a = (f32x4){0.f, 0.f, 0.f, 0.f};
      a = __builtin_amdgcn_mfma_f32_16x16x32_bf16(qf[mt][0], kf0, a, 0, 0, 0);
      a = __builtin_amdgcn_mfma_f32_16x16x32_bf16(qf[mt][1], kf1, a, 0, 0, 0);
      #pragma unroll
      for (int r = 0; r < 4; ++r) s[mt][nt][r] = a[r];
    }
  }

  // masked softmax in registers (row = mtile*16 + quad*4 + r, col = nt*16 + l15)
  #pragma unroll
  for (int mt = 0; mt < 2; ++mt) {
    int rowb = (wv * 2 + mt) * 16 + quad * 4;
    #pragma unroll
    for (int r = 0; r < 4; ++r) {
      int lim = rowb + r + 128;
      float mx = -3.0e38f;
      #pragma unroll
      for (int nt = 0; nt < 16; ++nt) {
        float v = ((nt * 16 + l15) <= lim) ? s[mt][nt][r] * 0.125f : -3.0e38f;
        s[mt][nt][r] = v;
        mx = fmaxf(mx, v);
      }
      mx = fmaxf(mx, __shfl_xor(mx, 1));
      mx = fmaxf(mx, __shfl_xor(mx, 2));
      mx = fmaxf(mx, __shfl_xor(mx, 4));
      mx = fmaxf(mx, __shfl_xor(mx, 8));
      float sum = 0.f;
      #pragma unroll
      for (int nt = 0; nt < 16; ++nt) {
        float p = __expf(s[mt][nt][r] - mx);   // masked -> exp(-huge) = 0
        s[mt][nt][r] = p;
        sum += p;
      }
      sum += __shfl_xor(sum, 1);
      sum += __shfl_xor(sum, 2);
      sum += __shfl_xor(sum, 4);
      sum += __shfl_xor(sum, 8);
      float inv = 1.f / sum;
      #pragma unroll
      for (int nt = 0; nt < 16; ++nt) s[mt][nt][r] *= inv;
    }
  }

  __syncthreads();   // all waves done reading Ksh -> safe to overlay P

  // PV: per m-tile, round-trip P through per-wave LDS region (C-layout -> A-layout)
  #pragma unroll
  for (int mt = 0; mt < 2; ++mt) {
    #pragma unroll
    for (int nt = 0; nt < 16; ++nt)
      #pragma unroll
      for (int r = 0; r < 4; ++r)
        Psh[wv * 4096 + (nt >> 1) * 512 + (quad * 4 + r) * 32 + (nt & 1) * 16 + l15] =
            f2bf(s[mt][nt][r]);
    __syncthreads();
    f32x4 o[4];
    #pragma unroll
    for (int n2 = 0; n2 < 4; ++n2) o[n2] = (f32x4){0.f, 0.f, 0.f, 0.f};
    #pragma unroll
    for (int ks = 0; ks < 8; ++ks) {
      bf16x8 pa = lds_frag(&Psh[wv * 4096 + ks * 512 + l15 * 32 + quad * 8]);
      #pragma unroll
      for (int n2 = 0; n2 < 4; ++n2) {
        bf16x8 vb = lds_frag(&VshT[(n2 * 16 + l15) * 256 + (((ks * 4 + quad) ^ (l15 & 7)) * 8)]);
        o[n2] = __builtin_amdgcn_mfma_f32_16x16x32_bf16(pa, vb, o[n2], 0, 0, 0);
      }
    }
    int tokb = w * 128 + (wv * 2 + mt) * 16 + quad * 4;
    #pragma unroll
    for (int n2 = 0; n2 < 4; ++n2)
      #pragma unroll
      for (int r = 0; r < 4; ++r)
        out[(size_t)(tokb + r) * 512 + h * 64 + n2 * 16 + l15] = f2bf(o[n2][r]);
    __syncthreads();
  }
}

extern "C" void kernel_launch(void* const* d_in, const int* in_sizes, int n_in,
                              void* d_out, int out_size, void* d_ws, size_t ws_size,
                              hipStream_t stream) {
  const float* x     = (const float*)d_in[0];  // 16384 x 1024 fp32
  const float* w_qkv = (const float*)d_in[1];  // 1024 x 1536 fp32
  const float* w_out = (const float*)d_in[2];  // 512 x 1024 fp32
  const float* b_out = (const float*)d_in[3];  // 1024 fp32
  float* out = (float*)d_out;                  // 16384 x 1024 fp32

  char* ws = (char*)d_ws;
  unsigned short* xb    = (unsigned short*)ws;                     // 16384x1024 bf16 (32 MB)
  unsigned short* wqkvT = (unsigned short*)(ws + 33554432);        // 1536x1024 (3 MB)
  unsigned short* woutT = (unsigned short*)(ws + 36700160);        // 1024x512  (1 MB)
  unsigned short* qkv   = (unsigned short*)(ws + 37748736);        // 16384x1536 (48 MB)
  unsigned short* attno = (unsigned short*)(ws + 88080384);        // 16384x512 (16 MB)

  cast_bf16_k<<<8192, 256, 0, stream>>>(x, xb, 16384 * 1024);
  transpose_cast_k<<<dim3(48, 32), 256, 0, stream>>>(w_qkv, wqkvT, 1024, 1536);
  transpose_cast_k<<<dim3(32, 16), 256, 0, stream>>>(w_out, woutT, 512, 1024);
  // QKV: 64 m-tiles x 6 n-tiles (256^2); 8 m-tiles per xcd
  gemm_bt256<unsigned short><<<384, 512, 0, stream>>>(
      xb, wqkvT, qkv, nullptr, 16384, 1536, 1024, 6, 8);
  attn_local<<<1024, 256, 0, stream>>>(qkv, attno);
  // out-proj: 64 m-tiles x 4 n-tiles (256^2); 8 m-tiles per xcd
  gemm_bt256<float><<<256, 512, 0, stream>>>(
      attno, woutT, out, b_out, 16384, 1024, 512, 4, 8);
}

// Round 5
// 236.639 us; speedup vs baseline: 1.1856x; 1.1856x over previous
//
#include <hip/hip_runtime.h>

using bf16x8 = __attribute__((ext_vector_type(8))) short;
using f32x4  = __attribute__((ext_vector_type(4))) float;
using u32x4  = __attribute__((ext_vector_type(4))) unsigned int;

__device__ __forceinline__ unsigned short f2bf(float f) {
  unsigned int u = __builtin_bit_cast(unsigned int, f);
  u += 0x7FFF + ((u >> 16) & 1);               // RNE
  return (unsigned short)(u >> 16);
}
__device__ __forceinline__ bf16x8 lds_frag(const unsigned short* p) {
  return __builtin_bit_cast(bf16x8, *(const u32x4*)p);
}
// async global->LDS, 16B per lane; LDS dest = wave-uniform base + lane*16
__device__ __forceinline__ void async_copy16(const unsigned short* g, unsigned short* l) {
  __builtin_amdgcn_global_load_lds(
      (const __attribute__((address_space(1))) unsigned int*)g,
      (__attribute__((address_space(3))) unsigned int*)l, 16, 0, 0);
}

// fp32 -> bf16 elementwise, 8 elems/thread
__global__ void cast_bf16_k(const float* __restrict__ in,
                            unsigned short* __restrict__ out, int n) {
  int i = (blockIdx.x * 256 + threadIdx.x) * 8;
  if (i < n) {
    unsigned short r[8];
    #pragma unroll
    for (int j = 0; j < 8; ++j) r[j] = f2bf(in[i + j]);
    *(u32x4*)&out[i] = *(u32x4*)r;
  }
}

// LDS-tiled transpose+cast: out[c*R+r] = bf16(in[r*C+c]). R,C multiples of 32.
__global__ void transpose_cast_k(const float* __restrict__ in,
                                 unsigned short* __restrict__ out, int R, int C) {
  __shared__ float tile[32][33];
  const int tx = threadIdx.x & 31, ty = threadIdx.x >> 5;   // 32 x 8
  const int c0 = blockIdx.x * 32, r0 = blockIdx.y * 32;
  #pragma unroll
  for (int i = 0; i < 4; ++i)
    tile[ty + i * 8][tx] = in[(size_t)(r0 + ty + i * 8) * C + c0 + tx];
  __syncthreads();
  #pragma unroll
  for (int i = 0; i < 4; ++i)
    out[(size_t)(c0 + ty + i * 8) * R + r0 + tx] = f2bf(tile[tx][ty + i * 8]);
}

// C[M,N] = A[M,K] @ Bt[N,K]^T (+bias for fp32 out), A/Bt bf16, fp32 accum.
// 128x128 tile, BK=64, global_load_lds staging with XOR bank swizzle
// (conflict-free, verified: SQ_LDS_BANK_CONFLICT == 0). Known-good m97
// structure: 3 blocks/CU gives implicit inter-block overlap that hides the
// barrier vmcnt drain (m114 mechanism) — measured 57.2 us / 37% MfmaUtil on
// the QKV shape. Deep-pipeline variants regressed twice (compiler inserts
// conservative vmcnt before dependent ds_reads; 1 block/CU removes TLP).
template <typename OutT>
__global__ __launch_bounds__(256, 3)
void gemm_bt(const unsigned short* __restrict__ A,
             const unsigned short* __restrict__ Bt,
             OutT* __restrict__ C,
             const float* __restrict__ bias,
             int M, int N, int K, int n_tiles, int mt_per_xcd) {
  __shared__ unsigned short Ash[128 * 64];   // 16 KB
  __shared__ unsigned short Bsh[128 * 64];   // 16 KB
  const int tid  = threadIdx.x;
  const int wv   = tid >> 6, lane = tid & 63;
  const int quad = lane >> 4, l15 = lane & 15;
  const int wr   = wv >> 1, wc = wv & 1;

  const int b = blockIdx.x;
  const int xcd = b & 7, local = b >> 3;
  const int mt = xcd * mt_per_xcd + local / n_tiles;
  const int nt = local % n_tiles;
  const int m0 = mt * 128, n0 = nt * 128;

  // staging: 1024 16B-groups per matrix; p in 0..3, lin = p*256+tid
  // LDS slot lin = (row = lin>>3, cg = lin&7); global group = cg ^ (row&7)
  const unsigned short* pA[4];
  const unsigned short* pB[4];
  #pragma unroll
  for (int p = 0; p < 4; ++p) {
    int lin = p * 256 + tid;
    int row = lin >> 3, g = (lin & 7) ^ (row & 7);
    pA[p] = &A[(size_t)(m0 + row) * K + g * 8];
    pB[p] = &Bt[(size_t)(n0 + row) * K + g * 8];
  }

  f32x4 acc[4][4];
  #pragma unroll
  for (int i = 0; i < 4; ++i)
    #pragma unroll
    for (int j = 0; j < 4; ++j)
      acc[i][j] = (f32x4){0.f, 0.f, 0.f, 0.f};

  for (int k0 = 0; k0 < K; k0 += 64) {
    #pragma unroll
    for (int p = 0; p < 4; ++p)
      async_copy16(pA[p] + k0, &Ash[(p * 256 + tid) * 8]);
    #pragma unroll
    for (int p = 0; p < 4; ++p)
      async_copy16(pB[p] + k0, &Bsh[(p * 256 + tid) * 8]);
    __syncthreads();
    #pragma unroll
    for (int ks = 0; ks < 2; ++ks) {
      const int swz = (((ks * 4 + quad) ^ (l15 & 7)) * 8);
      bf16x8 af[4], bfr[4];
      #pragma unroll
      for (int i = 0; i < 4; ++i)
        af[i] = lds_frag(&Ash[(wr * 64 + i * 16 + l15) * 64 + swz]);
      #pragma unroll
      for (int j = 0; j < 4; ++j)
        bfr[j] = lds_frag(&Bsh[(wc * 64 + j * 16 + l15) * 64 + swz]);
      #pragma unroll
      for (int i = 0; i < 4; ++i)
        #pragma unroll
        for (int j = 0; j < 4; ++j)
          acc[i][j] = __builtin_amdgcn_mfma_f32_16x16x32_bf16(af[i], bfr[j], acc[i][j], 0, 0, 0);
    }
    __syncthreads();
  }

  #pragma unroll
  for (int i = 0; i < 4; ++i) {
    #pragma unroll
    for (int j = 0; j < 4; ++j) {
      int col = n0 + wc * 64 + j * 16 + l15;
      float badd = (bias != nullptr) ? bias[col] : 0.f;
      #pragma unroll
      for (int r = 0; r < 4; ++r) {
        int row = m0 + wr * 64 + i * 16 + quad * 4 + r;
        if constexpr (sizeof(OutT) == 2)
          C[(size_t)row * N + col] = f2bf(acc[i][j][r] + badd);
        else
          C[(size_t)row * N + col] = acc[i][j][r] + badd;
      }
    }
  }
}

// Local attention: one block per (head, window). qkv: 16384 x 1536 bf16,
// out: 16384 x 512 bf16. WSZ=128, lookback window of 128 (zeros for w==0).
// mask: col <= row + 128. scale = 1/8.
// 512 threads / 8 waves: wave wv owns m-tile wv (rows wv*16..wv*16+15).
// TWO block-wide barriers (after staging; after QK^T reads). PV is SPLIT
// into two k-halves so the P overlay fits Ksh: per wave, half-P is 16 rows
// x 128 k = 4KB; 8 waves x 4KB = 32KB = Ksh exactly (round-4 bug: full P
// was 8KB/wave -> waves 4..7 spilled into VshT and corrupted V).
// P region is wave-private -> lgkmcnt(0)+sched_barrier fences, no barriers.
__global__ __launch_bounds__(512, 4)
void attn_local(const unsigned short* __restrict__ qkv,
                unsigned short* __restrict__ out) {
  // Ksh: [ks(2)][j(256)][32] (64B rows -> b128 frags). Psh overlays Ksh.
  // VshT: V^T col-major [n(64)][k(256)], XOR swizzle: 16B-group g of row n
  // at slot g^(n&7).
  __shared__ unsigned short Ksh[2 * 256 * 32];   // 32 KB
  __shared__ unsigned short VshT[64 * 256];      // 32 KB
  unsigned short* Psh = Ksh;

  const int tid  = threadIdx.x;
  const int wv   = tid >> 6, lane = tid & 63;
  const int quad = lane >> 4, l15 = lane & 15;
  const int h = blockIdx.x & 7, w = blockIdx.x >> 3;

  // stage K (k-tiled); rows j<128 of window 0 are zeros
  #pragma unroll
  for (int p = 0; p < 4; ++p) {
    int c = p * 512 + tid;                 // 2048 = 256 rows x 8 vec8-groups
    int j = c >> 3, sub = c & 7;
    u32x4 kvv = (u32x4){0, 0, 0, 0};
    if (!(w == 0 && j < 128)) {
      size_t base = (size_t)((w - 1) * 128 + j) * 1536 + h * 64 + sub * 8;
      kvv = *(const u32x4*)&qkv[base + 512];
    }
    *(u32x4*)&Ksh[(sub >> 2) * 8192 + j * 32 + (sub & 3) * 8] = kvv;
  }
  // stage V^T: thread (n = tid&63, kb8 = tid>>6) loads column n, 8 k's per iter
  {
    const int n = tid & 63, kb8 = tid >> 6;
    #pragma unroll
    for (int kk = 0; kk < 4; ++kk) {
      int kb = kk * 8 + kb8;               // group 0..31, k0 = kb*8
      unsigned short tmp[8];
      if (w == 0 && kb < 16) {
        #pragma unroll
        for (int j = 0; j < 8; ++j) tmp[j] = 0;
      } else {
        #pragma unroll
        for (int j = 0; j < 8; ++j)
          tmp[j] = qkv[(size_t)((w - 1) * 128 + kb * 8 + j) * 1536 + 1024 + h * 64 + n];
      }
      *(u32x4*)&VshT[n * 256 + ((kb ^ (n & 7)) * 8)] = *(u32x4*)tmp;
    }
  }

  // Q fragments straight from global (A-operand: row l15, k = ks*32+quad*8..+7)
  bf16x8 qf[2];
  {
    int tok = w * 128 + wv * 16 + l15;
    #pragma unroll
    for (int ks = 0; ks < 2; ++ks)
      qf[ks] = __builtin_bit_cast(
          bf16x8, *(const u32x4*)&qkv[(size_t)tok * 1536 + h * 64 + ks * 32 + quad * 8]);
  }

  __syncthreads();   // staging visible block-wide

  // scores: wave wv owns rows [wv*16, wv*16+16)
  float s[16][4];
  #pragma unroll
  for (int nt = 0; nt < 16; ++nt) {
    bf16x8 kf0 = lds_frag(&Ksh[0    + (nt * 16 + l15) * 32 + quad * 8]);
    bf16x8 kf1 = lds_frag(&Ksh[8192 + (nt * 16 + l15) * 32 + quad * 8]);
    f32x4 a = (f32x4){0.f, 0.f, 0.f, 0.f};
    a = __builtin_amdgcn_mfma_f32_16x16x32_bf16(qf[0], kf0, a, 0, 0, 0);
    a = __builtin_amdgcn_mfma_f32_16x16x32_bf16(qf[1], kf1, a, 0, 0, 0);
    #pragma unroll
    for (int r = 0; r < 4; ++r) s[nt][r] = a[r];
  }

  __syncthreads();   // all waves' Ksh reads complete -> safe to overlay P

  // masked softmax in registers (row = wv*16 + quad*4 + r, col = nt*16 + l15)
  #pragma unroll
  for (int r = 0; r < 4; ++r) {
    int lim = wv * 16 + quad * 4 + r + 128;
    float mx = -3.0e38f;
    #pragma unroll
    for (int nt = 0; nt < 16; ++nt) {
      float v = ((nt * 16 + l15) <= lim) ? s[nt][r] * 0.125f : -3.0e38f;
      s[nt][r] = v;
      mx = fmaxf(mx, v);
    }
    mx = fmaxf(mx, __shfl_xor(mx, 1));
    mx = fmaxf(mx, __shfl_xor(mx, 2));
    mx = fmaxf(mx, __shfl_xor(mx, 4));
    mx = fmaxf(mx, __shfl_xor(mx, 8));
    float sum = 0.f;
    #pragma unroll
    for (int nt = 0; nt < 16; ++nt) {
      float p = __expf(s[nt][r] - mx);     // masked -> exp(-huge) = 0
      s[nt][r] = p;
      sum += p;
    }
    sum += __shfl_xor(sum, 1);
    sum += __shfl_xor(sum, 2);
    sum += __shfl_xor(sum, 4);
    sum += __shfl_xor(sum, 8);
    float inv = 1.f / sum;
    #pragma unroll
    for (int nt = 0; nt < 16; ++nt) s[nt][r] *= inv;
  }

  // split PV: per half, round-trip half-P (16 rows x 128 k = 4KB) through the
  // wave-private region Psh[wv*2048 .. +2048). C-layout -> A-layout.
  // Fences are wave-local lgkm drains; ds ops can't cross the "memory" asm,
  // and sched_barrier(0) pins MFMA from hoisting past the drain (rule #18).
  f32x4 o[4];
  #pragma unroll
  for (int n2 = 0; n2 < 4; ++n2) o[n2] = (f32x4){0.f, 0.f, 0.f, 0.f};
  #pragma unroll
  for (int half = 0; half < 2; ++half) {
    if (half) {
      // phase-A reads fully returned before overwriting the region
      asm volatile("s_waitcnt lgkmcnt(0)" ::: "memory");
      __builtin_amdgcn_sched_barrier(0);
    }
    #pragma unroll
    for (int nt2 = 0; nt2 < 8; ++nt2) {
      int nt = half * 8 + nt2;
      #pragma unroll
      for (int r = 0; r < 4; ++r)
        Psh[wv * 2048 + (nt2 >> 1) * 512 + (quad * 4 + r) * 32 + (nt2 & 1) * 16 + l15] =
            f2bf(s[nt][r]);
    }
    asm volatile("s_waitcnt lgkmcnt(0)" ::: "memory");
    __builtin_amdgcn_sched_barrier(0);
    #pragma unroll
    for (int ks2 = 0; ks2 < 4; ++ks2) {
      int ks = half * 4 + ks2;             // global k-slot 0..7
      bf16x8 pa = lds_frag(&Psh[wv * 2048 + ks2 * 512 + l15 * 32 + quad * 8]);
      #pragma unroll
      for (int n2 = 0; n2 < 4; ++n2) {
        bf16x8 vb = lds_frag(&VshT[(n2 * 16 + l15) * 256 + (((ks * 4 + quad) ^ (l15 & 7)) * 8)]);
        o[n2] = __builtin_amdgcn_mfma_f32_16x16x32_bf16(pa, vb, o[n2], 0, 0, 0);
      }
    }
  }
  int tokb = w * 128 + wv * 16 + quad * 4;
  #pragma unroll
  for (int n2 = 0; n2 < 4; ++n2)
    #pragma unroll
    for (int r = 0; r < 4; ++r)
      out[(size_t)(tokb + r) * 512 + h * 64 + n2 * 16 + l15] = f2bf(o[n2][r]);
}

extern "C" void kernel_launch(void* const* d_in, const int* in_sizes, int n_in,
                              void* d_out, int out_size, void* d_ws, size_t ws_size,
                              hipStream_t stream) {
  const float* x     = (const float*)d_in[0];  // 16384 x 1024 fp32
  const float* w_qkv = (const float*)d_in[1];  // 1024 x 1536 fp32
  const float* w_out = (const float*)d_in[2];  // 512 x 1024 fp32
  const float* b_out = (const float*)d_in[3];  // 1024 fp32
  float* out = (float*)d_out;                  // 16384 x 1024 fp32

  char* ws = (char*)d_ws;
  unsigned short* xb    = (unsigned short*)ws;                     // 16384x1024 bf16 (32 MB)
  unsigned short* wqkvT = (unsigned short*)(ws + 33554432);        // 1536x1024 (3 MB)
  unsigned short* woutT = (unsigned short*)(ws + 36700160);        // 1024x512  (1 MB)
  unsigned short* qkv   = (unsigned short*)(ws + 37748736);        // 16384x1536 (48 MB)
  unsigned short* attno = (unsigned short*)(ws + 88080384);        // 16384x512 (16 MB)

  cast_bf16_k<<<8192, 256, 0, stream>>>(x, xb, 16384 * 1024);
  transpose_cast_k<<<dim3(48, 32), 256, 0, stream>>>(w_qkv, wqkvT, 1024, 1536);
  transpose_cast_k<<<dim3(32, 16), 256, 0, stream>>>(w_out, woutT, 512, 1024);
  // QKV: 128 m-tiles x 12 n-tiles; 16 m-tiles per xcd
  gemm_bt<unsigned short><<<1536, 256, 0, stream>>>(
      xb, wqkvT, qkv, nullptr, 16384, 1536, 1024, 12, 16);
  attn_local<<<1024, 512, 0, stream>>>(qkv, attno);
  // out-proj: 128 m-tiles x 8 n-tiles; 16 m-tiles per xcd
  gemm_bt<float><<<1024, 256, 0, stream>>>(
      attno, woutT, out, b_out, 16384, 1024, 512, 8, 16);
}

// Round 6
// 229.442 us; speedup vs baseline: 1.2228x; 1.0314x over previous
//
#include <hip/hip_runtime.h>

using bf16x8 = __attribute__((ext_vector_type(8))) short;
using f32x4  = __attribute__((ext_vector_type(4))) float;
using u32x4  = __attribute__((ext_vector_type(4))) unsigned int;

__device__ __forceinline__ unsigned short f2bf(float f) {
  unsigned int u = __builtin_bit_cast(unsigned int, f);
  u += 0x7FFF + ((u >> 16) & 1);               // RNE
  return (unsigned short)(u >> 16);
}
__device__ __forceinline__ bf16x8 lds_frag(const unsigned short* p) {
  return __builtin_bit_cast(bf16x8, *(const u32x4*)p);
}
// async global->LDS, 16B per lane; LDS dest = wave-uniform base + lane*16
__device__ __forceinline__ void async_copy16(const unsigned short* g, unsigned short* l) {
  __builtin_amdgcn_global_load_lds(
      (const __attribute__((address_space(1))) unsigned int*)g,
      (__attribute__((address_space(3))) unsigned int*)l, 16, 0, 0);
}

// Fused prep: one dispatch replaces cast_bf16 (8192 blocks) + transpose w_qkv
// (1536) + transpose w_out (512). Branch on blockIdx range (block-uniform, so
// the __syncthreads in the transpose path is safe). Tests the launch-gap
// hypothesis: 6 dispatches -> 4 with zero change to the hot kernels.
__global__ void prep_k(const float* __restrict__ x, unsigned short* __restrict__ xb,
                       const float* __restrict__ w_qkv, unsigned short* __restrict__ wqkvT,
                       const float* __restrict__ w_out, unsigned short* __restrict__ woutT) {
  __shared__ float tile[32][33];
  const int b = blockIdx.x;
  if (b < 8192) {
    // fp32 -> bf16 elementwise, 8 elems/thread (16384x1024 = 16.7M elems)
    int i = (b * 256 + threadIdx.x) * 8;
    if (i < 16384 * 1024) {
      unsigned short r[8];
      #pragma unroll
      for (int j = 0; j < 8; ++j) r[j] = f2bf(x[i + j]);
      *(u32x4*)&xb[i] = *(u32x4*)r;
    }
    return;
  }
  // LDS-tiled transpose+cast: out[c*R+r] = bf16(in[r*C+c])
  const float* in;
  unsigned short* out;
  int R, C, bx, by;
  if (b < 8192 + 1536) {                   // w_qkv: 1024x1536, grid 48x32
    int lb = b - 8192;
    bx = lb % 48; by = lb / 48;
    in = w_qkv; out = wqkvT; R = 1024; C = 1536;
  } else {                                 // w_out: 512x1024, grid 32x16
    int lb = b - 9728;
    bx = lb % 32; by = lb / 32;
    in = w_out; out = woutT; R = 512; C = 1024;
  }
  const int tx = threadIdx.x & 31, ty = threadIdx.x >> 5;   // 32 x 8
  const int c0 = bx * 32, r0 = by * 32;
  #pragma unroll
  for (int i = 0; i < 4; ++i)
    tile[ty + i * 8][tx] = in[(size_t)(r0 + ty + i * 8) * C + c0 + tx];
  __syncthreads();
  #pragma unroll
  for (int i = 0; i < 4; ++i)
    out[(size_t)(c0 + ty + i * 8) * R + r0 + tx] = f2bf(tile[tx][ty + i * 8]);
}

// C[M,N] = A[M,K] @ Bt[N,K]^T (+bias for fp32 out), A/Bt bf16, fp32 accum.
// 128x128 tile, BK=64, global_load_lds staging with XOR bank swizzle
// (conflict-free, verified: SQ_LDS_BANK_CONFLICT == 0). Known-good m97
// structure: 3 blocks/CU gives implicit inter-block overlap that hides the
// barrier vmcnt drain (m114 mechanism) — measured 56.5-57.2 us / 37-39%
// MfmaUtil on the QKV shape. Deep-pipeline variants regressed twice.
template <typename OutT>
__global__ __launch_bounds__(256, 3)
void gemm_bt(const unsigned short* __restrict__ A,
             const unsigned short* __restrict__ Bt,
             OutT* __restrict__ C,
             const float* __restrict__ bias,
             int M, int N, int K, int n_tiles, int mt_per_xcd) {
  __shared__ unsigned short Ash[128 * 64];   // 16 KB
  __shared__ unsigned short Bsh[128 * 64];   // 16 KB
  const int tid  = threadIdx.x;
  const int wv   = tid >> 6, lane = tid & 63;
  const int quad = lane >> 4, l15 = lane & 15;
  const int wr   = wv >> 1, wc = wv & 1;

  const int b = blockIdx.x;
  const int xcd = b & 7, local = b >> 3;
  const int mt = xcd * mt_per_xcd + local / n_tiles;
  const int nt = local % n_tiles;
  const int m0 = mt * 128, n0 = nt * 128;

  // staging: 1024 16B-groups per matrix; p in 0..3, lin = p*256+tid
  // LDS slot lin = (row = lin>>3, cg = lin&7); global group = cg ^ (row&7)
  const unsigned short* pA[4];
  const unsigned short* pB[4];
  #pragma unroll
  for (int p = 0; p < 4; ++p) {
    int lin = p * 256 + tid;
    int row = lin >> 3, g = (lin & 7) ^ (row & 7);
    pA[p] = &A[(size_t)(m0 + row) * K + g * 8];
    pB[p] = &Bt[(size_t)(n0 + row) * K + g * 8];
  }

  f32x4 acc[4][4];
  #pragma unroll
  for (int i = 0; i < 4; ++i)
    #pragma unroll
    for (int j = 0; j < 4; ++j)
      acc[i][j] = (f32x4){0.f, 0.f, 0.f, 0.f};

  for (int k0 = 0; k0 < K; k0 += 64) {
    #pragma unroll
    for (int p = 0; p < 4; ++p)
      async_copy16(pA[p] + k0, &Ash[(p * 256 + tid) * 8]);
    #pragma unroll
    for (int p = 0; p < 4; ++p)
      async_copy16(pB[p] + k0, &Bsh[(p * 256 + tid) * 8]);
    __syncthreads();
    #pragma unroll
    for (int ks = 0; ks < 2; ++ks) {
      const int swz = (((ks * 4 + quad) ^ (l15 & 7)) * 8);
      bf16x8 af[4], bfr[4];
      #pragma unroll
      for (int i = 0; i < 4; ++i)
        af[i] = lds_frag(&Ash[(wr * 64 + i * 16 + l15) * 64 + swz]);
      #pragma unroll
      for (int j = 0; j < 4; ++j)
        bfr[j] = lds_frag(&Bsh[(wc * 64 + j * 16 + l15) * 64 + swz]);
      #pragma unroll
      for (int i = 0; i < 4; ++i)
        #pragma unroll
        for (int j = 0; j < 4; ++j)
          acc[i][j] = __builtin_amdgcn_mfma_f32_16x16x32_bf16(af[i], bfr[j], acc[i][j], 0, 0, 0);
    }
    __syncthreads();
  }

  #pragma unroll
  for (int i = 0; i < 4; ++i) {
    #pragma unroll
    for (int j = 0; j < 4; ++j) {
      int col = n0 + wc * 64 + j * 16 + l15;
      float badd = (bias != nullptr) ? bias[col] : 0.f;
      #pragma unroll
      for (int r = 0; r < 4; ++r) {
        int row = m0 + wr * 64 + i * 16 + quad * 4 + r;
        if constexpr (sizeof(OutT) == 2)
          C[(size_t)row * N + col] = f2bf(acc[i][j][r] + badd);
        else
          C[(size_t)row * N + col] = acc[i][j][r] + badd;
      }
    }
  }
}

// Local attention: one block per (head, window). qkv: 16384 x 1536 bf16,
// out: 16384 x 512 bf16. WSZ=128, lookback window of 128 (zeros for w==0).
// mask: col <= row + 128. scale = 1/8.
// 512 threads / 8 waves: wave wv owns m-tile wv (rows wv*16..wv*16+15).
// TWO block-wide barriers (after staging; after QK^T reads). PV is SPLIT
// into two k-halves so the P overlay fits Ksh: per wave, half-P is 16 rows
// x 128 k = 4KB; 8 waves x 4KB = 32KB = Ksh exactly.
// P region is wave-private -> lgkmcnt(0)+sched_barrier fences, no barriers.
__global__ __launch_bounds__(512, 4)
void attn_local(const unsigned short* __restrict__ qkv,
                unsigned short* __restrict__ out) {
  // Ksh: [ks(2)][j(256)][32] (64B rows -> b128 frags). Psh overlays Ksh.
  // VshT: V^T col-major [n(64)][k(256)], XOR swizzle: 16B-group g of row n
  // at slot g^(n&7).
  __shared__ unsigned short Ksh[2 * 256 * 32];   // 32 KB
  __shared__ unsigned short VshT[64 * 256];      // 32 KB
  unsigned short* Psh = Ksh;

  const int tid  = threadIdx.x;
  const int wv   = tid >> 6, lane = tid & 63;
  const int quad = lane >> 4, l15 = lane & 15;
  const int h = blockIdx.x & 7, w = blockIdx.x >> 3;

  // stage K (k-tiled); rows j<128 of window 0 are zeros
  #pragma unroll
  for (int p = 0; p < 4; ++p) {
    int c = p * 512 + tid;                 // 2048 = 256 rows x 8 vec8-groups
    int j = c >> 3, sub = c & 7;
    u32x4 kvv = (u32x4){0, 0, 0, 0};
    if (!(w == 0 && j < 128)) {
      size_t base = (size_t)((w - 1) * 128 + j) * 1536 + h * 64 + sub * 8;
      kvv = *(const u32x4*)&qkv[base + 512];
    }
    *(u32x4*)&Ksh[(sub >> 2) * 8192 + j * 32 + (sub & 3) * 8] = kvv;
  }
  // stage V^T: thread (n = tid&63, kb8 = tid>>6) loads column n, 8 k's per iter
  {
    const int n = tid & 63, kb8 = tid >> 6;
    #pragma unroll
    for (int kk = 0; kk < 4; ++kk) {
      int kb = kk * 8 + kb8;               // group 0..31, k0 = kb*8
      unsigned short tmp[8];
      if (w == 0 && kb < 16) {
        #pragma unroll
        for (int j = 0; j < 8; ++j) tmp[j] = 0;
      } else {
        #pragma unroll
        for (int j = 0; j < 8; ++j)
          tmp[j] = qkv[(size_t)((w - 1) * 128 + kb * 8 + j) * 1536 + 1024 + h * 64 + n];
      }
      *(u32x4*)&VshT[n * 256 + ((kb ^ (n & 7)) * 8)] = *(u32x4*)tmp;
    }
  }

  // Q fragments straight from global (A-operand: row l15, k = ks*32+quad*8..+7)
  bf16x8 qf[2];
  {
    int tok = w * 128 + wv * 16 + l15;
    #pragma unroll
    for (int ks = 0; ks < 2; ++ks)
      qf[ks] = __builtin_bit_cast(
          bf16x8, *(const u32x4*)&qkv[(size_t)tok * 1536 + h * 64 + ks * 32 + quad * 8]);
  }

  __syncthreads();   // staging visible block-wide

  // scores: wave wv owns rows [wv*16, wv*16+16)
  float s[16][4];
  #pragma unroll
  for (int nt = 0; nt < 16; ++nt) {
    bf16x8 kf0 = lds_frag(&Ksh[0    + (nt * 16 + l15) * 32 + quad * 8]);
    bf16x8 kf1 = lds_frag(&Ksh[8192 + (nt * 16 + l15) * 32 + quad * 8]);
    f32x4 a = (f32x4){0.f, 0.f, 0.f, 0.f};
    a = __builtin_amdgcn_mfma_f32_16x16x32_bf16(qf[0], kf0, a, 0, 0, 0);
    a = __builtin_amdgcn_mfma_f32_16x16x32_bf16(qf[1], kf1, a, 0, 0, 0);
    #pragma unroll
    for (int r = 0; r < 4; ++r) s[nt][r] = a[r];
  }

  __syncthreads();   // all waves' Ksh reads complete -> safe to overlay P

  // masked softmax in registers (row = wv*16 + quad*4 + r, col = nt*16 + l15)
  #pragma unroll
  for (int r = 0; r < 4; ++r) {
    int lim = wv * 16 + quad * 4 + r + 128;
    float mx = -3.0e38f;
    #pragma unroll
    for (int nt = 0; nt < 16; ++nt) {
      float v = ((nt * 16 + l15) <= lim) ? s[nt][r] * 0.125f : -3.0e38f;
      s[nt][r] = v;
      mx = fmaxf(mx, v);
    }
    mx = fmaxf(mx, __shfl_xor(mx, 1));
    mx = fmaxf(mx, __shfl_xor(mx, 2));
    mx = fmaxf(mx, __shfl_xor(mx, 4));
    mx = fmaxf(mx, __shfl_xor(mx, 8));
    float sum = 0.f;
    #pragma unroll
    for (int nt = 0; nt < 16; ++nt) {
      float p = __expf(s[nt][r] - mx);     // masked -> exp(-huge) = 0
      s[nt][r] = p;
      sum += p;
    }
    sum += __shfl_xor(sum, 1);
    sum += __shfl_xor(sum, 2);
    sum += __shfl_xor(sum, 4);
    sum += __shfl_xor(sum, 8);
    float inv = 1.f / sum;
    #pragma unroll
    for (int nt = 0; nt < 16; ++nt) s[nt][r] *= inv;
  }

  // split PV: per half, round-trip half-P (16 rows x 128 k = 4KB) through the
  // wave-private region Psh[wv*2048 .. +2048). C-layout -> A-layout.
  // Fences are wave-local lgkm drains; ds ops can't cross the "memory" asm,
  // and sched_barrier(0) pins MFMA from hoisting past the drain (rule #18).
  f32x4 o[4];
  #pragma unroll
  for (int n2 = 0; n2 < 4; ++n2) o[n2] = (f32x4){0.f, 0.f, 0.f, 0.f};
  #pragma unroll
  for (int half = 0; half < 2; ++half) {
    if (half) {
      // phase-A reads fully returned before overwriting the region
      asm volatile("s_waitcnt lgkmcnt(0)" ::: "memory");
      __builtin_amdgcn_sched_barrier(0);
    }
    #pragma unroll
    for (int nt2 = 0; nt2 < 8; ++nt2) {
      int nt = half * 8 + nt2;
      #pragma unroll
      for (int r = 0; r < 4; ++r)
        Psh[wv * 2048 + (nt2 >> 1) * 512 + (quad * 4 + r) * 32 + (nt2 & 1) * 16 + l15] =
            f2bf(s[nt][r]);
    }
    asm volatile("s_waitcnt lgkmcnt(0)" ::: "memory");
    __builtin_amdgcn_sched_barrier(0);
    #pragma unroll
    for (int ks2 = 0; ks2 < 4; ++ks2) {
      int ks = half * 4 + ks2;             // global k-slot 0..7
      bf16x8 pa = lds_frag(&Psh[wv * 2048 + ks2 * 512 + l15 * 32 + quad * 8]);
      #pragma unroll
      for (int n2 = 0; n2 < 4; ++n2) {
        bf16x8 vb = lds_frag(&VshT[(n2 * 16 + l15) * 256 + (((ks * 4 + quad) ^ (l15 & 7)) * 8)]);
        o[n2] = __builtin_amdgcn_mfma_f32_16x16x32_bf16(pa, vb, o[n2], 0, 0, 0);
      }
    }
  }
  int tokb = w * 128 + wv * 16 + quad * 4;
  #pragma unroll
  for (int n2 = 0; n2 < 4; ++n2)
    #pragma unroll
    for (int r = 0; r < 4; ++r)
      out[(size_t)(tokb + r) * 512 + h * 64 + n2 * 16 + l15] = f2bf(o[n2][r]);
}

extern "C" void kernel_launch(void* const* d_in, const int* in_sizes, int n_in,
                              void* d_out, int out_size, void* d_ws, size_t ws_size,
                              hipStream_t stream) {
  const float* x     = (const float*)d_in[0];  // 16384 x 1024 fp32
  const float* w_qkv = (const float*)d_in[1];  // 1024 x 1536 fp32
  const float* w_out = (const float*)d_in[2];  // 512 x 1024 fp32
  const float* b_out = (const float*)d_in[3];  // 1024 fp32
  float* out = (float*)d_out;                  // 16384 x 1024 fp32

  char* ws = (char*)d_ws;
  unsigned short* xb    = (unsigned short*)ws;                     // 16384x1024 bf16 (32 MB)
  unsigned short* wqkvT = (unsigned short*)(ws + 33554432);        // 1536x1024 (3 MB)
  unsigned short* woutT = (unsigned short*)(ws + 36700160);        // 1024x512  (1 MB)
  unsigned short* qkv   = (unsigned short*)(ws + 37748736);        // 16384x1536 (48 MB)
  unsigned short* attno = (unsigned short*)(ws + 88080384);        // 16384x512 (16 MB)

  // fused prep: cast (8192 blocks) + transpose w_qkv (1536) + transpose w_out (512)
  prep_k<<<10240, 256, 0, stream>>>(x, xb, w_qkv, wqkvT, w_out, woutT);
  // QKV: 128 m-tiles x 12 n-tiles; 16 m-tiles per xcd
  gemm_bt<unsigned short><<<1536, 256, 0, stream>>>(
      xb, wqkvT, qkv, nullptr, 16384, 1536, 1024, 12, 16);
  attn_local<<<1024, 512, 0, stream>>>(qkv, attno);
  // out-proj: 128 m-tiles x 8 n-tiles; 16 m-tiles per xcd
  gemm_bt<float><<<1024, 256, 0, stream>>>(
      attno, woutT, out, b_out, 16384, 1024, 512, 8, 16);
}